// Round 2
// baseline (6239.933 us; speedup 1.0000x reference)
//
#include <hip/hip_runtime.h>

#define TT 2048
#define LL 50
#define DD 300
#define HH 100
#define NCC 7

typedef unsigned short u16;
typedef unsigned int u32;

__device__ __forceinline__ u32 fkey(float f){ u32 u; __builtin_memcpy(&u, &f, 4); return (u & 0x80000000u) ? ~u : (u | 0x80000000u); }
__device__ __forceinline__ float funkey(u32 k){ u32 u = (k & 0x80000000u) ? (k & 0x7FFFFFFFu) : ~k; float f; __builtin_memcpy(&f, &u, 4); return f; }
__device__ __forceinline__ float sigm(float x){ return 1.f / (1.f + __expf(-x)); }

// ---------------- Kernel 1: embedding + TextCNN(3,4,5) + max-relu + s_utt ----------------
#define WROW 304   // padded LDS row stride (floats)
__global__ __launch_bounds__(256) void k_cnn(const int* __restrict__ sents,
    const float* __restrict__ emb,
    const float* __restrict__ Wc3, const float* __restrict__ bc3,
    const float* __restrict__ Wc4, const float* __restrict__ bc4,
    const float* __restrict__ Wc5, const float* __restrict__ bc5,
    const float* __restrict__ Wt,  const float* __restrict__ bt,
    float* __restrict__ su)
{
  __shared__ float w[52 * WROW];       // 52 rows (50 words + 2 zero pad), 304 floats each
  __shared__ int ids[LL];
  __shared__ u32 feats_u[192];         // monotone-key atomicMax, later reused as float bits
  const int tid = threadIdx.x;
  const int s = blockIdx.x;

  if (tid < LL) ids[tid] = sents[s * LL + tid];
  for (int e = tid; e < 52 * WROW; e += 256) w[e] = 0.f;
  if (tid < 192) feats_u[tid] = 0u;
  __syncthreads();
  // 50 rows * 75 float4 each = 3750 vector loads (rows are 16B-aligned: 300 % 4 == 0)
  for (int e = tid; e < LL * 75; e += 256){
    int l = e / 75, d4 = (e - l * 75) * 4;
    *(float4*)&w[l * WROW + d4] = *(const float4*)&emb[(size_t)ids[l] * DD + d4];
  }
  __syncthreads();

  // 288 tasks: task = pc*48 + F  (F fastest so lanes broadcast the same A rows)
  for (int task = tid; task < 288; task += 256){
    int pc = task / 48;
    int F  = task - pc * 48;
    int kk, fbase, colbase; const float* W;
    if (F < 16){ kk = 3; fbase = F * 4;         W = Wc3; colbase = fbase; }
    else if (F < 32){ kk = 4; fbase = (F-16)*4; W = Wc4; colbase = 64 + fbase; }
    else { kk = 5; fbase = (F-32)*4;            W = Wc5; colbase = 128 + fbase; }
    int pos0 = pc * 8;
    float acc[4][8];
    #pragma unroll
    for (int fi = 0; fi < 4; ++fi)
      #pragma unroll
      for (int p = 0; p < 8; ++p) acc[fi][p] = 0.f;

    for (int j = 0; j < kk; ++j){
      const float* wr = W + (size_t)(fbase * kk + j) * DD;
      for (int d = 0; d < DD; d += 4){
        float4 a[8];
        #pragma unroll
        for (int p = 0; p < 8; ++p) a[p] = *(const float4*)&w[(pos0 + p + j) * WROW + d];
        #pragma unroll
        for (int fi = 0; fi < 4; ++fi){
          float4 wv = *(const float4*)(wr + (size_t)fi * kk * DD + d);
          #pragma unroll
          for (int p = 0; p < 8; ++p)
            acc[fi][p] += a[p].x * wv.x + a[p].y * wv.y + a[p].z * wv.z + a[p].w * wv.w;
        }
      }
    }
    int Pk = LL - kk + 1;   // 48 / 47 / 46 valid positions
    #pragma unroll
    for (int fi = 0; fi < 4; ++fi){
      float m = -1e30f;
      #pragma unroll
      for (int p = 0; p < 8; ++p) if (pos0 + p < Pk) m = fmaxf(m, acc[fi][p]);
      atomicMax(&feats_u[colbase + fi], fkey(m));
    }
  }
  __syncthreads();
  if (tid < 192){
    float m = funkey(feats_u[tid]);
    float bias = (tid < 64) ? bc3[tid] : ((tid < 128) ? bc4[tid - 64] : bc5[tid - 128]);
    feats_u[tid] = __float_as_uint(fmaxf(0.f, m + bias));   // relu(max(y)+b) == max(relu(y+b))
  }
  __syncthreads();
  if (tid < HH){
    float acc = bt[tid];
    for (int c = 0; c < 192; ++c)
      acc += __uint_as_float(feats_u[c]) * Wt[c * HH + tid];
    su[(size_t)s * HH + tid] = tanhf(acc);
  }
}

// ---------------- Kernel 2/4: gi = src @ Wih^T + bih   (rows x 300) ----------------
__global__ __launch_bounds__(320) void k_gi(const float* __restrict__ src,
    const float* __restrict__ W, const float* __restrict__ b, float* __restrict__ dst)
{
  __shared__ float x[HH];
  const int t = blockIdx.x, tid = threadIdx.x;
  if (tid < HH) x[tid] = src[(size_t)t * HH + tid];
  __syncthreads();
  if (tid < 300){
    float acc = b[tid];
    const float* wr = W + (size_t)tid * HH;
    #pragma unroll
    for (int i = 0; i < 25; ++i){
      float4 wv = *(const float4*)(wr + 4 * i);
      float4 xv = *(const float4*)&x[4 * i];
      acc += xv.x * wv.x + xv.y * wv.y + xv.z * wv.z + xv.w * wv.w;
    }
    dst[(size_t)t * 300 + tid] = acc;
  }
}

// ---------------- Kernel 3: sequential context-GRU scan (1 workgroup) ----------------
__global__ __launch_bounds__(320) void k_scan(const float* __restrict__ gi,
    const float* __restrict__ Whh, const float* __restrict__ bhh,
    float* __restrict__ hid, int steps)
{
  __shared__ float hbuf[104];
  __shared__ float gh_l[300];
  __shared__ float bh_l[300];
  const int tid = threadIdx.x;
  float wreg[104];
  if (tid < 300){
    #pragma unroll
    for (int i = 0; i < 25; ++i)
      *(float4*)&wreg[4 * i] = *(const float4*)&Whh[(size_t)tid * 100 + 4 * i];
    wreg[100] = wreg[101] = wreg[102] = wreg[103] = 0.f;
    bh_l[tid] = bhh[tid];
  }
  if (tid < 104) hbuf[tid] = 0.f;
  __syncthreads();
  for (int t = 0; t < steps; ++t){
    if (tid < 300){
      float a0 = 0, a1 = 0, a2 = 0, a3 = 0;
      #pragma unroll
      for (int i = 0; i < 26; ++i){
        float4 h4 = *(const float4*)&hbuf[4 * i];
        a0 += h4.x * wreg[4*i]; a1 += h4.y * wreg[4*i+1];
        a2 += h4.z * wreg[4*i+2]; a3 += h4.w * wreg[4*i+3];
      }
      gh_l[tid] = (a0 + a1) + (a2 + a3);
    }
    __syncthreads();
    if (tid < 50){
      const float* gr = gi + (size_t)t * 300;
      int h0 = 2 * tid;
      float o0, o1;
      {
        float ghr0 = gh_l[h0]     + bh_l[h0],     ghr1 = gh_l[h0+1]   + bh_l[h0+1];
        float ghz0 = gh_l[h0+100] + bh_l[h0+100], ghz1 = gh_l[h0+101] + bh_l[h0+101];
        float ghn0 = gh_l[h0+200] + bh_l[h0+200], ghn1 = gh_l[h0+201] + bh_l[h0+201];
        float r0 = sigm(gr[h0]     + ghr0), r1 = sigm(gr[h0+1]   + ghr1);
        float z0 = sigm(gr[h0+100] + ghz0), z1 = sigm(gr[h0+101] + ghz1);
        float n0 = tanhf(gr[h0+200] + r0 * ghn0), n1 = tanhf(gr[h0+201] + r1 * ghn1);
        float hv0 = hbuf[h0], hv1 = hbuf[h0+1];
        o0 = (1.f - z0) * n0 + z0 * hv0;
        o1 = (1.f - z1) * n1 + z1 * hv1;
      }
      *(float2*)&hbuf[h0] = make_float2(o0, o1);
      *(float2*)&hid[(size_t)t * HH + h0] = make_float2(o0, o1);
    }
    __syncthreads();
  }
}

// ---------------- Kernel 5: 3-hop windowed memory attention (1 block / query) ----------------
__global__ __launch_bounds__(320) void k_att(
    const float* __restrict__ su, const float* __restrict__ hid, const float* __restrict__ gm,
    const float* __restrict__ Wih, const float* __restrict__ Whh,
    const float* __restrict__ bih, const float* __restrict__ bhh,
    float* __restrict__ scont)
{
  __shared__ float mem_l[40 * 104];
  __shared__ float hbuf[104];
  __shared__ float gh_l[300];
  __shared__ float q_l[104];
  __shared__ float sc_l[40];
  __shared__ float bi_l[300], bh_l[300];
  __shared__ _Float16 gi2[40 * 300];
  const int tid = threadIdx.x;
  const int q = blockIdx.x;                 // query q -> sentence q+1
  int wmin = 39 - q; if (wmin < 0) wmin = 0;
  float wreg[104];

  if (tid < 300){ bi_l[tid] = bih[tid]; bh_l[tid] = bhh[tid]; }
  if (tid < 104) q_l[tid] = (tid < 100) ? su[(size_t)(q + 1) * HH + tid] : 0.f;
  for (int e = tid; e < 40 * 104; e += 320){
    int w = e / 104, i = e - w * 104;
    float v = 0.f;
    if (i < 100 && w >= wmin) v = hid[(size_t)(q - 39 + w) * HH + i];
    mem_l[e] = v;
  }
  if (tid < 300){
    #pragma unroll
    for (int i = 0; i < 25; ++i)
      *(float4*)&wreg[4 * i] = *(const float4*)&Whh[(size_t)tid * 100 + 4 * i];
    wreg[100] = wreg[101] = wreg[102] = wreg[103] = 0.f;
  }
  __syncthreads();

  for (int hop = 0; hop < 3; ++hop){
    // --- attention: scores ---
    if (tid < 40){
      float a0 = 0, a1 = 0, a2 = 0, a3 = 0;
      const float* mr = &mem_l[tid * 104];
      #pragma unroll
      for (int i = 0; i < 26; ++i){
        float4 m4 = *(const float4*)&mr[4 * i];
        float4 q4 = *(const float4*)&q_l[4 * i];
        a0 += m4.x * q4.x; a1 += m4.y * q4.y; a2 += m4.z * q4.z; a3 += m4.w * q4.w;
      }
      sc_l[tid] = (tid >= wmin) ? ((a0 + a1) + (a2 + a3)) : -1e10f;
    }
    __syncthreads();
    if (tid < 64){
      float v = (tid < 40) ? sc_l[tid] : -3e38f;
      float m = v;
      #pragma unroll
      for (int off = 32; off; off >>= 1) m = fmaxf(m, __shfl_xor(m, off));
      float e = (tid < 40) ? __expf(v - m) : 0.f;
      float ssum = e;
      #pragma unroll
      for (int off = 32; off; off >>= 1) ssum += __shfl_xor(ssum, off);
      if (tid < 40) sc_l[tid] = e / ssum;
    }
    __syncthreads();
    // --- attention: context + query update ---
    if (tid < 50){
      float c0 = 0.f, c1 = 0.f;
      for (int w = wmin; w < 40; ++w){
        float a = sc_l[w];
        float2 mv = *(const float2*)&mem_l[w * 104 + 2 * tid];
        c0 += a * mv.x; c1 += a * mv.y;
      }
      float q0 = tanhf(q_l[2 * tid]     + c0);
      float q1 = tanhf(q_l[2 * tid + 1] + c1);
      *(float2*)&q_l[2 * tid] = make_float2(q0, q1);
      if (hop == 2)
        *(float2*)&scont[(size_t)(q + 1) * HH + 2 * tid] = make_float2(q0, q1);
    }
    if (hop == 2) break;

    if (hop == 1){
      // gi2 = mem @ Wih^T + bih  (mem is post-scan1 state)
      if (tid < 300){
        #pragma unroll
        for (int i = 0; i < 25; ++i)
          *(float4*)&wreg[4 * i] = *(const float4*)&Wih[(size_t)tid * 100 + 4 * i];
        wreg[100] = wreg[101] = wreg[102] = wreg[103] = 0.f;
      }
      __syncthreads();
      if (tid < 300){
        for (int w = 0; w < 40; ++w){
          float a0 = 0, a1 = 0, a2 = 0, a3 = 0;
          const float* mr = &mem_l[w * 104];
          #pragma unroll
          for (int i = 0; i < 26; ++i){
            float4 m4 = *(const float4*)&mr[4 * i];
            a0 += m4.x * wreg[4*i]; a1 += m4.y * wreg[4*i+1];
            a2 += m4.z * wreg[4*i+2]; a3 += m4.w * wreg[4*i+3];
          }
          gi2[w * 300 + tid] = (_Float16)((a0 + a1) + (a2 + a3) + bi_l[tid]);
        }
        // restore Whh for scan2
        #pragma unroll
        for (int i = 0; i < 25; ++i)
          *(float4*)&wreg[4 * i] = *(const float4*)&Whh[(size_t)tid * 100 + 4 * i];
        wreg[100] = wreg[101] = wreg[102] = wreg[103] = 0.f;
      }
    }

    // --- memory GRU scan over the 40 slots ---
    if (tid < 104) hbuf[tid] = 0.f;
    __syncthreads();
    for (int w = 0; w < 40; ++w){
      if (tid < 300){
        float a0 = 0, a1 = 0, a2 = 0, a3 = 0;
        #pragma unroll
        for (int i = 0; i < 26; ++i){
          float4 h4 = *(const float4*)&hbuf[4 * i];
          a0 += h4.x * wreg[4*i]; a1 += h4.y * wreg[4*i+1];
          a2 += h4.z * wreg[4*i+2]; a3 += h4.w * wreg[4*i+3];
        }
        gh_l[tid] = (a0 + a1) + (a2 + a3);
      }
      __syncthreads();
      if (tid < 50){
        int h0 = 2 * tid;
        float o0 = hbuf[h0], o1 = hbuf[h0 + 1];
        if (w >= wmin){
          float gir0, giz0, gin0, gir1, giz1, gin1;
          if (hop == 0){
            const float* gp = &gm[(size_t)(q - 39 + w) * 300];
            gir0 = gp[h0];       gir1 = gp[h0+1];
            giz0 = gp[h0+100];   giz1 = gp[h0+101];
            gin0 = gp[h0+200];   gin1 = gp[h0+201];
          } else {
            const _Float16* gp = &gi2[w * 300];
            gir0 = (float)gp[h0];     gir1 = (float)gp[h0+1];
            giz0 = (float)gp[h0+100]; giz1 = (float)gp[h0+101];
            gin0 = (float)gp[h0+200]; gin1 = (float)gp[h0+201];
          }
          float ghr0 = gh_l[h0]     + bh_l[h0],     ghr1 = gh_l[h0+1]   + bh_l[h0+1];
          float ghz0 = gh_l[h0+100] + bh_l[h0+100], ghz1 = gh_l[h0+101] + bh_l[h0+101];
          float ghn0 = gh_l[h0+200] + bh_l[h0+200], ghn1 = gh_l[h0+201] + bh_l[h0+201];
          float r0 = sigm(gir0 + ghr0), r1 = sigm(gir1 + ghr1);
          float z0 = sigm(giz0 + ghz0), z1 = sigm(giz1 + ghz1);
          float n0 = tanhf(gin0 + r0 * ghn0), n1 = tanhf(gin1 + r1 * ghn1);
          o0 = (1.f - z0) * n0 + z0 * o0;
          o1 = (1.f - z1) * n1 + z1 * o1;
        }
        *(float2*)&hbuf[h0] = make_float2(o0, o1);
        *(float2*)&mem_l[w * 104 + h0] = make_float2(o0, o1);   // scan emits hm at every slot
      }
      __syncthreads();
    }
  }
}

// ---------------- Kernel 6: classifier + log_softmax ----------------
__global__ __launch_bounds__(256) void k_cls(const float* __restrict__ su, const float* __restrict__ scont,
    const float* __restrict__ Wcls, const float* __restrict__ bcls, float* __restrict__ out)
{
  __shared__ float wl[HH * NCC];
  __shared__ float bl[NCC];
  const int tid = threadIdx.x;
  for (int e = tid; e < HH * NCC; e += 256) wl[e] = Wcls[e];
  if (tid < NCC) bl[tid] = bcls[tid];
  __syncthreads();
  int r = blockIdx.x * 256 + tid;
  if (r < TT){
    const float* v = (r == 0) ? su : (scont + (size_t)r * HH);
    float l[NCC];
    #pragma unroll
    for (int c = 0; c < NCC; ++c) l[c] = bl[c];
    for (int h = 0; h < HH; ++h){
      float x = v[h];
      #pragma unroll
      for (int c = 0; c < NCC; ++c) l[c] += x * wl[h * NCC + c];
    }
    float m = l[0];
    #pragma unroll
    for (int c = 1; c < NCC; ++c) m = fmaxf(m, l[c]);
    float ssum = 0.f;
    #pragma unroll
    for (int c = 0; c < NCC; ++c) ssum += __expf(l[c] - m);
    float lse = m + __logf(ssum);
    #pragma unroll
    for (int c = 0; c < NCC; ++c) out[(size_t)r * NCC + c] = l[c] - lse;
  }
}

extern "C" void kernel_launch(void* const* d_in, const int* in_sizes, int n_in,
                              void* d_out, int out_size, void* d_ws, size_t ws_size,
                              hipStream_t stream)
{
  const int* sents  = (const int*)d_in[0];
  // d_in[1] = lengths (unused by the reference)
  const float* emb    = (const float*)d_in[2];
  const float* Wc3    = (const float*)d_in[3];  const float* bc3 = (const float*)d_in[4];
  const float* Wc4    = (const float*)d_in[5];  const float* bc4 = (const float*)d_in[6];
  const float* Wc5    = (const float*)d_in[7];  const float* bc5 = (const float*)d_in[8];
  const float* Wt     = (const float*)d_in[9];  const float* bt  = (const float*)d_in[10];
  const float* Wih_c  = (const float*)d_in[11]; const float* Whh_c = (const float*)d_in[12];
  const float* bih_c  = (const float*)d_in[13]; const float* bhh_c = (const float*)d_in[14];
  const float* Wih_m  = (const float*)d_in[15]; const float* Whh_m = (const float*)d_in[16];
  const float* bih_m  = (const float*)d_in[17]; const float* bhh_m = (const float*)d_in[18];
  const float* Wcls   = (const float*)d_in[19]; const float* bcls  = (const float*)d_in[20];

  float* ws    = (float*)d_ws;
  float* su    = ws;                  // 2048*100           = 204800
  float* gic   = su  + 204800;        // 2047*300           = 614100
  float* hid   = gic + 614100;        // 2047*100           = 204700
  float* gm    = hid + 204700;        // 2047*300           = 614100
  float* scont = gm  + 614100;        // 2048*100           = 204800   (row 0 unused)

  k_cnn <<<TT,      256, 0, stream>>>(sents, emb, Wc3, bc3, Wc4, bc4, Wc5, bc5, Wt, bt, su);
  k_gi  <<<TT - 1,  320, 0, stream>>>(su, Wih_c, bih_c, gic);
  k_scan<<<1,       320, 0, stream>>>(gic, Whh_c, bhh_c, hid, TT - 1);
  k_gi  <<<TT - 1,  320, 0, stream>>>(hid, Wih_m, bih_m, gm);
  k_att <<<TT - 1,  320, 0, stream>>>(su, hid, gm, Wih_m, Whh_m, bih_m, bhh_m, scont);
  k_cls <<<(TT + 255) / 256, 256, 0, stream>>>(su, scont, Wcls, bcls, (float*)d_out);
}

// Round 3
// 5074.397 us; speedup vs baseline: 1.2297x; 1.2297x over previous
//
#include <hip/hip_runtime.h>

#define TT 2048
#define LL 50
#define DD 300
#define HH 100
#define NCC 7

typedef unsigned short u16;
typedef unsigned int u32;

__device__ __forceinline__ u32 fkey(float f){ u32 u; __builtin_memcpy(&u, &f, 4); return (u & 0x80000000u) ? ~u : (u | 0x80000000u); }
__device__ __forceinline__ float funkey(u32 k){ u32 u = (k & 0x80000000u) ? (k & 0x7FFFFFFFu) : ~k; float f; __builtin_memcpy(&f, &u, 4); return f; }
// fast transcendentals: v_exp_f32 + v_rcp_f32, short dependency chains
__device__ __forceinline__ float frcp(float x){ return __builtin_amdgcn_rcpf(x); }
__device__ __forceinline__ float sigm(float x){ return frcp(1.f + __expf(-x)); }
__device__ __forceinline__ float ftanh(float x){ return 1.f - 2.f * frcp(1.f + __expf(2.f * x)); }

// ---------------- Kernel 1: embedding + TextCNN(3,4,5) + max-relu + s_utt ----------------
#define WROW 304   // padded LDS row stride (floats)
__global__ __launch_bounds__(256) void k_cnn(const int* __restrict__ sents,
    const float* __restrict__ emb,
    const float* __restrict__ Wc3, const float* __restrict__ bc3,
    const float* __restrict__ Wc4, const float* __restrict__ bc4,
    const float* __restrict__ Wc5, const float* __restrict__ bc5,
    const float* __restrict__ Wt,  const float* __restrict__ bt,
    float* __restrict__ su)
{
  __shared__ float w[52 * WROW];       // 52 rows (50 words + 2 zero pad), 304 floats each
  __shared__ int ids[LL];
  __shared__ u32 feats_u[192];         // monotone-key atomicMax, later reused as float bits
  const int tid = threadIdx.x;
  const int s = blockIdx.x;

  if (tid < LL) ids[tid] = sents[s * LL + tid];
  for (int e = tid; e < 52 * WROW; e += 256) w[e] = 0.f;
  if (tid < 192) feats_u[tid] = 0u;
  __syncthreads();
  for (int e = tid; e < LL * 75; e += 256){
    int l = e / 75, d4 = (e - l * 75) * 4;
    *(float4*)&w[l * WROW + d4] = *(const float4*)&emb[(size_t)ids[l] * DD + d4];
  }
  __syncthreads();

  // 288 tasks: task = pc*48 + F  (F fastest so lanes broadcast the same A rows)
  for (int task = tid; task < 288; task += 256){
    int pc = task / 48;
    int F  = task - pc * 48;
    int kk, fbase, colbase; const float* W;
    if (F < 16){ kk = 3; fbase = F * 4;         W = Wc3; colbase = fbase; }
    else if (F < 32){ kk = 4; fbase = (F-16)*4; W = Wc4; colbase = 64 + fbase; }
    else { kk = 5; fbase = (F-32)*4;            W = Wc5; colbase = 128 + fbase; }
    int pos0 = pc * 8;
    float acc[4][8];
    #pragma unroll
    for (int fi = 0; fi < 4; ++fi)
      #pragma unroll
      for (int p = 0; p < 8; ++p) acc[fi][p] = 0.f;

    for (int j = 0; j < kk; ++j){
      const float* wr = W + (size_t)(fbase * kk + j) * DD;
      for (int d = 0; d < DD; d += 4){
        float4 a[8];
        #pragma unroll
        for (int p = 0; p < 8; ++p) a[p] = *(const float4*)&w[(pos0 + p + j) * WROW + d];
        #pragma unroll
        for (int fi = 0; fi < 4; ++fi){
          float4 wv = *(const float4*)(wr + (size_t)fi * kk * DD + d);
          #pragma unroll
          for (int p = 0; p < 8; ++p)
            acc[fi][p] += a[p].x * wv.x + a[p].y * wv.y + a[p].z * wv.z + a[p].w * wv.w;
        }
      }
    }
    int Pk = LL - kk + 1;   // 48 / 47 / 46 valid positions
    #pragma unroll
    for (int fi = 0; fi < 4; ++fi){
      float m = -1e30f;
      #pragma unroll
      for (int p = 0; p < 8; ++p) if (pos0 + p < Pk) m = fmaxf(m, acc[fi][p]);
      atomicMax(&feats_u[colbase + fi], fkey(m));
    }
  }
  __syncthreads();
  if (tid < 192){
    float m = funkey(feats_u[tid]);
    float bias = (tid < 64) ? bc3[tid] : ((tid < 128) ? bc4[tid - 64] : bc5[tid - 128]);
    feats_u[tid] = __float_as_uint(fmaxf(0.f, m + bias));   // relu(max(y)+b) == max(relu(y+b))
  }
  __syncthreads();
  if (tid < HH){
    float acc = bt[tid];
    for (int c = 0; c < 192; ++c)
      acc += __uint_as_float(feats_u[c]) * Wt[c * HH + tid];
    su[(size_t)s * HH + tid] = ftanh(acc);
  }
}

// ---------------- Kernel 2/4: gi = src @ Wih^T + bih   (rows x 300) ----------------
__global__ __launch_bounds__(320) void k_gi(const float* __restrict__ src,
    const float* __restrict__ W, const float* __restrict__ b, float* __restrict__ dst)
{
  __shared__ float x[HH];
  const int t = blockIdx.x, tid = threadIdx.x;
  if (tid < HH) x[tid] = src[(size_t)t * HH + tid];
  __syncthreads();
  if (tid < 300){
    float acc = b[tid];
    const float* wr = W + (size_t)tid * HH;
    #pragma unroll
    for (int i = 0; i < 25; ++i){
      float4 wv = *(const float4*)(wr + 4 * i);
      float4 xv = *(const float4*)&x[4 * i];
      acc += xv.x * wv.x + xv.y * wv.y + xv.z * wv.z + xv.w * wv.w;
    }
    dst[(size_t)t * 300 + tid] = acc;
  }
}

// ---------------- Kernel 3: sequential context-GRU scan (1 workgroup) ----------------
// Per step: [300 lanes] gi_l<=prefetched reg; matvec gh=Whh@h+bh; prefetch gi[t+1]
//           barrier; [100 lanes] gates w/ fast exp; h'->LDS+global; barrier.
__global__ __launch_bounds__(320) void k_scan(const float* __restrict__ gi,
    const float* __restrict__ Whh, const float* __restrict__ bhh,
    float* __restrict__ hid, int steps)
{
  __shared__ float hbuf[HH];
  __shared__ float gh_l[300];
  __shared__ float gi_l[300];
  const int tid = threadIdx.x;
  float wreg[100];
  float bh = 0.f;
  if (tid < 300){
    #pragma unroll
    for (int i = 0; i < 25; ++i)
      *(float4*)&wreg[4 * i] = *(const float4*)&Whh[(size_t)tid * 100 + 4 * i];
    bh = bhh[tid];
  }
  if (tid < HH) hbuf[tid] = 0.f;
  float gval = (tid < 300) ? gi[tid] : 0.f;   // step-0 prefetch
  __syncthreads();
  for (int t = 0; t < steps; ++t){
    if (tid < 300){
      gi_l[tid] = gval;
      float a0 = 0, a1 = 0, a2 = 0, a3 = 0;
      #pragma unroll
      for (int i = 0; i < 25; ++i){
        float4 h4 = *(const float4*)&hbuf[4 * i];
        a0 += h4.x * wreg[4*i]; a1 += h4.y * wreg[4*i+1];
        a2 += h4.z * wreg[4*i+2]; a3 += h4.w * wreg[4*i+3];
      }
      gh_l[tid] = (a0 + a1) + (a2 + a3) + bh;
      if (t + 1 < steps) gval = gi[(size_t)(t + 1) * 300 + tid];   // hide global latency
    }
    __syncthreads();
    if (tid < HH){
      float ghr = gh_l[tid], ghz = gh_l[tid + 100], ghn = gh_l[tid + 200];
      float gir = gi_l[tid], giz = gi_l[tid + 100], gin = gi_l[tid + 200];
      float hv = hbuf[tid];
      float r = sigm(gir + ghr);
      float z = sigm(giz + ghz);
      float n = ftanh(gin + r * ghn);
      float o = (1.f - z) * n + z * hv;
      hbuf[tid] = o;
      hid[(size_t)t * HH + tid] = o;
    }
    __syncthreads();
  }
}

// ---------------- Kernel 5: 3-hop windowed memory attention (1 block / query) ----------------
__global__ __launch_bounds__(320) void k_att(
    const float* __restrict__ su, const float* __restrict__ hid, const float* __restrict__ gm,
    const float* __restrict__ Wih, const float* __restrict__ Whh,
    const float* __restrict__ bih, const float* __restrict__ bhh,
    float* __restrict__ scont)
{
  __shared__ float mem_l[40 * 104];
  __shared__ float hbuf[HH];
  __shared__ float gh_l[300];
  __shared__ float q_l[104];
  __shared__ float sc_l[40];
  __shared__ float bi_l[300];
  __shared__ _Float16 g_l[40 * 300];   // hop0: staged gm (incl. bias); hop1: computed gi2
  const int tid = threadIdx.x;
  const int q = blockIdx.x;                 // query q -> sentence q+1
  int wmin = 39 - q; if (wmin < 0) wmin = 0;
  float wreg[100];
  float bh = 0.f;

  if (tid < 300){ bi_l[tid] = bih[tid]; bh = bhh[tid]; }
  if (tid < 104) q_l[tid] = (tid < 100) ? su[(size_t)(q + 1) * HH + tid] : 0.f;
  for (int e = tid; e < 40 * 104; e += 320){
    int w = e / 104, i = e - w * 104;
    float v = 0.f;
    if (i < 100 && w >= wmin) v = hid[(size_t)(q - 39 + w) * HH + i];
    mem_l[e] = v;
  }
  // stage the gm window into LDS (f16): removes global loads from the scan chain
  for (int e = tid; e < 40 * 300; e += 320){
    int w = e / 300, j = e - w * 300;
    float v = (w >= wmin) ? gm[(size_t)(q - 39 + w) * 300 + j] : 0.f;
    g_l[e] = (_Float16)v;
  }
  if (tid < 300){
    #pragma unroll
    for (int i = 0; i < 25; ++i)
      *(float4*)&wreg[4 * i] = *(const float4*)&Whh[(size_t)tid * 100 + 4 * i];
  }
  __syncthreads();

  for (int hop = 0; hop < 3; ++hop){
    // --- attention: scores ---
    if (tid < 40){
      float a0 = 0, a1 = 0, a2 = 0, a3 = 0;
      const float* mr = &mem_l[tid * 104];
      #pragma unroll
      for (int i = 0; i < 25; ++i){
        float4 m4 = *(const float4*)&mr[4 * i];
        float4 q4 = *(const float4*)&q_l[4 * i];
        a0 += m4.x * q4.x; a1 += m4.y * q4.y; a2 += m4.z * q4.z; a3 += m4.w * q4.w;
      }
      sc_l[tid] = (tid >= wmin) ? ((a0 + a1) + (a2 + a3)) : -1e10f;
    }
    __syncthreads();
    if (tid < 64){
      float v = (tid < 40) ? sc_l[tid] : -3e38f;
      float m = v;
      #pragma unroll
      for (int off = 32; off; off >>= 1) m = fmaxf(m, __shfl_xor(m, off));
      float e = (tid < 40) ? __expf(v - m) : 0.f;
      float ssum = e;
      #pragma unroll
      for (int off = 32; off; off >>= 1) ssum += __shfl_xor(ssum, off);
      if (tid < 40) sc_l[tid] = e * frcp(ssum);
    }
    __syncthreads();
    // --- attention: context + query update ---
    if (tid < 50){
      float c0 = 0.f, c1 = 0.f;
      for (int w = wmin; w < 40; ++w){
        float a = sc_l[w];
        float2 mv = *(const float2*)&mem_l[w * 104 + 2 * tid];
        c0 += a * mv.x; c1 += a * mv.y;
      }
      float q0 = ftanh(q_l[2 * tid]     + c0);
      float q1 = ftanh(q_l[2 * tid + 1] + c1);
      *(float2*)&q_l[2 * tid] = make_float2(q0, q1);
      if (hop == 2)
        *(float2*)&scont[(size_t)(q + 1) * HH + 2 * tid] = make_float2(q0, q1);
    }
    if (hop == 2) break;

    if (hop == 1){
      // g_l = mem @ Wih^T + bih  (mem is post-scan1 state; overwrites gm staging)
      if (tid < 300){
        #pragma unroll
        for (int i = 0; i < 25; ++i)
          *(float4*)&wreg[4 * i] = *(const float4*)&Wih[(size_t)tid * 100 + 4 * i];
        for (int w = 0; w < 40; ++w){
          float a0 = 0, a1 = 0, a2 = 0, a3 = 0;
          const float* mr = &mem_l[w * 104];
          #pragma unroll
          for (int i = 0; i < 25; ++i){
            float4 m4 = *(const float4*)&mr[4 * i];
            a0 += m4.x * wreg[4*i]; a1 += m4.y * wreg[4*i+1];
            a2 += m4.z * wreg[4*i+2]; a3 += m4.w * wreg[4*i+3];
          }
          g_l[w * 300 + tid] = (_Float16)((a0 + a1) + (a2 + a3) + bi_l[tid]);
        }
        // restore Whh for scan2
        #pragma unroll
        for (int i = 0; i < 25; ++i)
          *(float4*)&wreg[4 * i] = *(const float4*)&Whh[(size_t)tid * 100 + 4 * i];
      }
    }

    // --- memory GRU scan over the 40 slots ---
    if (tid < HH) hbuf[tid] = 0.f;
    __syncthreads();   // also orders g_l writes (hop1) before scan reads
    for (int w = 0; w < 40; ++w){
      if (tid < 300){
        float a0 = 0, a1 = 0, a2 = 0, a3 = 0;
        #pragma unroll
        for (int i = 0; i < 25; ++i){
          float4 h4 = *(const float4*)&hbuf[4 * i];
          a0 += h4.x * wreg[4*i]; a1 += h4.y * wreg[4*i+1];
          a2 += h4.z * wreg[4*i+2]; a3 += h4.w * wreg[4*i+3];
        }
        gh_l[tid] = (a0 + a1) + (a2 + a3) + bh;
      }
      __syncthreads();
      if (tid < HH){
        float o = hbuf[tid];
        if (w >= wmin){
          const _Float16* gp = &g_l[w * 300];
          float gir = (float)gp[tid], giz = (float)gp[tid + 100], gin = (float)gp[tid + 200];
          float r = sigm(gir + gh_l[tid]);
          float z = sigm(giz + gh_l[tid + 100]);
          float n = ftanh(gin + r * gh_l[tid + 200]);
          o = (1.f - z) * n + z * o;
        }
        hbuf[tid] = o;
        mem_l[w * 104 + tid] = o;   // scan emits hm at every slot
      }
      __syncthreads();
    }
  }
}

// ---------------- Kernel 6: classifier + log_softmax ----------------
__global__ __launch_bounds__(256) void k_cls(const float* __restrict__ su, const float* __restrict__ scont,
    const float* __restrict__ Wcls, const float* __restrict__ bcls, float* __restrict__ out)
{
  __shared__ float wl[HH * NCC];
  __shared__ float bl[NCC];
  const int tid = threadIdx.x;
  for (int e = tid; e < HH * NCC; e += 256) wl[e] = Wcls[e];
  if (tid < NCC) bl[tid] = bcls[tid];
  __syncthreads();
  int r = blockIdx.x * 256 + tid;
  if (r < TT){
    const float* v = (r == 0) ? su : (scont + (size_t)r * HH);
    float l[NCC];
    #pragma unroll
    for (int c = 0; c < NCC; ++c) l[c] = bl[c];
    for (int h = 0; h < HH; ++h){
      float x = v[h];
      #pragma unroll
      for (int c = 0; c < NCC; ++c) l[c] += x * wl[h * NCC + c];
    }
    float m = l[0];
    #pragma unroll
    for (int c = 1; c < NCC; ++c) m = fmaxf(m, l[c]);
    float ssum = 0.f;
    #pragma unroll
    for (int c = 0; c < NCC; ++c) ssum += __expf(l[c] - m);
    float lse = m + __logf(ssum);
    #pragma unroll
    for (int c = 0; c < NCC; ++c) out[(size_t)r * NCC + c] = l[c] - lse;
  }
}

extern "C" void kernel_launch(void* const* d_in, const int* in_sizes, int n_in,
                              void* d_out, int out_size, void* d_ws, size_t ws_size,
                              hipStream_t stream)
{
  const int* sents  = (const int*)d_in[0];
  // d_in[1] = lengths (unused by the reference)
  const float* emb    = (const float*)d_in[2];
  const float* Wc3    = (const float*)d_in[3];  const float* bc3 = (const float*)d_in[4];
  const float* Wc4    = (const float*)d_in[5];  const float* bc4 = (const float*)d_in[6];
  const float* Wc5    = (const float*)d_in[7];  const float* bc5 = (const float*)d_in[8];
  const float* Wt     = (const float*)d_in[9];  const float* bt  = (const float*)d_in[10];
  const float* Wih_c  = (const float*)d_in[11]; const float* Whh_c = (const float*)d_in[12];
  const float* bih_c  = (const float*)d_in[13]; const float* bhh_c = (const float*)d_in[14];
  const float* Wih_m  = (const float*)d_in[15]; const float* Whh_m = (const float*)d_in[16];
  const float* bih_m  = (const float*)d_in[17]; const float* bhh_m = (const float*)d_in[18];
  const float* Wcls   = (const float*)d_in[19]; const float* bcls  = (const float*)d_in[20];

  float* ws    = (float*)d_ws;
  float* su    = ws;                  // 2048*100
  float* gic   = su  + 204800;        // 2047*300
  float* hid   = gic + 614100;        // 2047*100
  float* gm    = hid + 204700;        // 2047*300
  float* scont = gm  + 614100;        // 2048*100 (row 0 unused)

  k_cnn <<<TT,      256, 0, stream>>>(sents, emb, Wc3, bc3, Wc4, bc4, Wc5, bc5, Wt, bt, su);
  k_gi  <<<TT - 1,  320, 0, stream>>>(su, Wih_c, bih_c, gic);
  k_scan<<<1,       320, 0, stream>>>(gic, Whh_c, bhh_c, hid, TT - 1);
  k_gi  <<<TT - 1,  320, 0, stream>>>(hid, Wih_m, bih_m, gm);
  k_att <<<TT - 1,  320, 0, stream>>>(su, hid, gm, Wih_m, Whh_m, bih_m, bhh_m, scont);
  k_cls <<<(TT + 255) / 256, 256, 0, stream>>>(su, scont, Wcls, bcls, (float*)d_out);
}

// Round 4
// 4389.007 us; speedup vs baseline: 1.4217x; 1.1562x over previous
//
#include <hip/hip_runtime.h>

#define TT 2048
#define LL 50
#define DD 300
#define HH 100
#define NCC 7

typedef unsigned short u16;
typedef unsigned int u32;

__device__ __forceinline__ u32 fkey(float f){ u32 u; __builtin_memcpy(&u, &f, 4); return (u & 0x80000000u) ? ~u : (u | 0x80000000u); }
__device__ __forceinline__ float funkey(u32 k){ u32 u = (k & 0x80000000u) ? (k & 0x7FFFFFFFu) : ~k; float f; __builtin_memcpy(&f, &u, 4); return f; }
// fast transcendentals: v_exp_f32 + v_rcp_f32, short dependency chains
__device__ __forceinline__ float frcp(float x){ return __builtin_amdgcn_rcpf(x); }
__device__ __forceinline__ float sigm(float x){ return frcp(1.f + __expf(-x)); }
__device__ __forceinline__ float ftanh(float x){ return 1.f - 2.f * frcp(1.f + __expf(2.f * x)); }

// ---------------- Kernel 1: embedding + TextCNN(3,4,5) + max-relu + s_utt ----------------
// LDS tile layout: row stride 304, plus +4 floats per 8-row group so that the
// 6 pc-group addresses inside one a[p] b128 read land on disjoint 4-bank groups
// (8*304 % 32 == 0 was a same-bank 2-way conflict; +4/group staggers them).
#define WROW 304
__device__ __forceinline__ int widx(int pos, int d){ return pos * WROW + (pos >> 3) * 4 + d; }
#define WSZ (52 * WROW + 7 * 4)

__global__ __launch_bounds__(256) void k_cnn(const int* __restrict__ sents,
    const float* __restrict__ emb,
    const float* __restrict__ Wc3, const float* __restrict__ bc3,
    const float* __restrict__ Wc4, const float* __restrict__ bc4,
    const float* __restrict__ Wc5, const float* __restrict__ bc5,
    const float* __restrict__ Wt,  const float* __restrict__ bt,
    float* __restrict__ su)
{
  __shared__ float w[WSZ];
  __shared__ int ids[LL];
  __shared__ u32 feats_u[192];         // monotone-key atomicMax, later reused as float bits
  const int tid = threadIdx.x;
  const int s = blockIdx.x;

  if (tid < LL) ids[tid] = sents[s * LL + tid];
  for (int e = tid; e < WSZ; e += 256) w[e] = 0.f;
  if (tid < 192) feats_u[tid] = 0u;
  __syncthreads();
  for (int e = tid; e < LL * 75; e += 256){
    int l = e / 75, d4 = (e - l * 75) * 4;
    *(float4*)&w[widx(l, d4)] = *(const float4*)&emb[(size_t)ids[l] * DD + d4];
  }
  __syncthreads();

  // 288 tasks, pc FASTEST: 6 consecutive lanes share one filter-quad F
  // -> weight loads are ~11 distinct rows/wave (broadcast), not 64.
  for (int task = tid; task < 288; task += 256){
    int F  = task / 6;
    int pc = task - F * 6;
    int kk, fbase, colbase; const float* W;
    if (F < 16){ kk = 3; fbase = F * 4;         W = Wc3; colbase = fbase; }
    else if (F < 32){ kk = 4; fbase = (F-16)*4; W = Wc4; colbase = 64 + fbase; }
    else { kk = 5; fbase = (F-32)*4;            W = Wc5; colbase = 128 + fbase; }
    int pos0 = pc * 8;
    float acc[4][8];
    #pragma unroll
    for (int fi = 0; fi < 4; ++fi)
      #pragma unroll
      for (int p = 0; p < 8; ++p) acc[fi][p] = 0.f;

    for (int j = 0; j < kk; ++j){
      const float* wr = W + (size_t)(fbase * kk + j) * DD;
      int rb[8];
      #pragma unroll
      for (int p = 0; p < 8; ++p) rb[p] = widx(pos0 + p + j, 0);
      for (int d = 0; d < DD; d += 4){
        float4 a[8];
        #pragma unroll
        for (int p = 0; p < 8; ++p) a[p] = *(const float4*)&w[rb[p] + d];
        #pragma unroll
        for (int fi = 0; fi < 4; ++fi){
          float4 wv = *(const float4*)(wr + (size_t)fi * kk * DD + d);
          #pragma unroll
          for (int p = 0; p < 8; ++p)
            acc[fi][p] += a[p].x * wv.x + a[p].y * wv.y + a[p].z * wv.z + a[p].w * wv.w;
        }
      }
    }
    int Pk = LL - kk + 1;   // 48 / 47 / 46 valid positions
    #pragma unroll
    for (int fi = 0; fi < 4; ++fi){
      float m = -1e30f;
      #pragma unroll
      for (int p = 0; p < 8; ++p) if (pos0 + p < Pk) m = fmaxf(m, acc[fi][p]);
      atomicMax(&feats_u[colbase + fi], fkey(m));
    }
  }
  __syncthreads();
  if (tid < 192){
    float m = funkey(feats_u[tid]);
    float bias = (tid < 64) ? bc3[tid] : ((tid < 128) ? bc4[tid - 64] : bc5[tid - 128]);
    feats_u[tid] = __float_as_uint(fmaxf(0.f, m + bias));   // relu(max(y)+b) == max(relu(y+b))
  }
  __syncthreads();
  if (tid < HH){
    float acc = bt[tid];
    for (int c = 0; c < 192; ++c)
      acc += __uint_as_float(feats_u[c]) * Wt[c * HH + tid];
    su[(size_t)s * HH + tid] = ftanh(acc);
  }
}

// ---------------- Kernel 2/4: gi = src @ Wih^T + bih   (rows x 300) ----------------
__global__ __launch_bounds__(320) void k_gi(const float* __restrict__ src,
    const float* __restrict__ W, const float* __restrict__ b, float* __restrict__ dst)
{
  __shared__ float x[HH];
  const int t = blockIdx.x, tid = threadIdx.x;
  if (tid < HH) x[tid] = src[(size_t)t * HH + tid];
  __syncthreads();
  if (tid < 300){
    float acc = b[tid];
    const float* wr = W + (size_t)tid * HH;
    #pragma unroll
    for (int i = 0; i < 25; ++i){
      float4 wv = *(const float4*)(wr + 4 * i);
      float4 xv = *(const float4*)&x[4 * i];
      acc += xv.x * wv.x + xv.y * wv.y + xv.z * wv.z + xv.w * wv.w;
    }
    dst[(size_t)t * 300 + tid] = acc;
  }
}

// ---------------- Kernel 3: sequential context-GRU scan (1 workgroup) ----------------
// Chunked: gi staged into LDS 16 steps at a time, hid buffered in LDS and
// flushed once per chunk -> the 2 per-step barriers carry NO outstanding vmem,
// so the compiler's vmcnt(0)-before-s_barrier drain happens once per 16 steps.
#define CH 16
__global__ __launch_bounds__(320) void k_scan(const float* __restrict__ gi,
    const float* __restrict__ Whh, const float* __restrict__ bhh,
    float* __restrict__ hid, int steps)
{
  __shared__ float hbuf[HH];
  __shared__ float gh_l[300];
  __shared__ float gi_buf[CH * 300];
  __shared__ float hid_buf[CH * HH];
  const int tid = threadIdx.x;
  float wreg[100];
  float bh = 0.f;
  if (tid < 300){
    #pragma unroll
    for (int i = 0; i < 25; ++i)
      *(float4*)&wreg[4 * i] = *(const float4*)&Whh[(size_t)tid * 100 + 4 * i];
    bh = bhh[tid];
  }
  if (tid < HH) hbuf[tid] = 0.f;
  {
    int c0 = (steps < CH ? steps : CH) * 75;
    for (int e = tid; e < c0; e += 320)
      ((float4*)gi_buf)[e] = ((const float4*)gi)[e];
  }
  __syncthreads();

  int t0 = 0;
  while (t0 < steps){
    int cnt = steps - t0; if (cnt > CH) cnt = CH;
    for (int s = 0; s < cnt; ++s){
      if (tid < 300){
        float a0 = 0, a1 = 0, a2 = 0, a3 = 0;
        #pragma unroll
        for (int i = 0; i < 25; ++i){
          float4 h4 = *(const float4*)&hbuf[4 * i];
          a0 += h4.x * wreg[4*i]; a1 += h4.y * wreg[4*i+1];
          a2 += h4.z * wreg[4*i+2]; a3 += h4.w * wreg[4*i+3];
        }
        gh_l[tid] = (a0 + a1) + (a2 + a3) + bh;
      }
      __syncthreads();
      if (tid < HH){
        const float* gr = &gi_buf[s * 300];
        float r = sigm(gr[tid]       + gh_l[tid]);
        float z = sigm(gr[tid + 100] + gh_l[tid + 100]);
        float n = ftanh(gr[tid + 200] + r * gh_l[tid + 200]);
        float o = (1.f - z) * n + z * hbuf[tid];
        hbuf[tid] = o;
        hid_buf[s * HH + tid] = o;
      }
      __syncthreads();
    }
    // chunk boundary: flush hid, stage next gi chunk (one vmcnt drain / CH steps)
    for (int e = tid; e < cnt * 25; e += 320)
      ((float4*)(hid + (size_t)t0 * HH))[e] = ((const float4*)hid_buf)[e];
    int nt0 = t0 + cnt;
    int ncnt = steps - nt0; if (ncnt > CH) ncnt = CH; if (ncnt < 0) ncnt = 0;
    for (int e = tid; e < ncnt * 75; e += 320)
      ((float4*)gi_buf)[e] = ((const float4*)(gi + (size_t)nt0 * 300))[e];
    __syncthreads();
    t0 = nt0;
  }
}

// ---------------- Kernel 5: 3-hop windowed memory attention (1 block / query) ----------------
__global__ __launch_bounds__(320) void k_att(
    const float* __restrict__ su, const float* __restrict__ hid, const float* __restrict__ gm,
    const float* __restrict__ Wih, const float* __restrict__ Whh,
    const float* __restrict__ bih, const float* __restrict__ bhh,
    float* __restrict__ scont)
{
  __shared__ float mem_l[40 * 104];
  __shared__ float hbuf[HH];
  __shared__ float gh_l[300];
  __shared__ float q_l[104];
  __shared__ float sc_l[40];
  __shared__ float bi_l[300];
  __shared__ _Float16 g_l[40 * 300];   // hop0: staged gm (incl. bias); hop1: computed gi2
  const int tid = threadIdx.x;
  const int q = blockIdx.x;                 // query q -> sentence q+1
  int wmin = 39 - q; if (wmin < 0) wmin = 0;
  float wreg[100];
  float bh = 0.f;

  if (tid < 300){ bi_l[tid] = bih[tid]; bh = bhh[tid]; }
  if (tid < 104) q_l[tid] = (tid < 100) ? su[(size_t)(q + 1) * HH + tid] : 0.f;
  for (int e = tid; e < 40 * 104; e += 320){
    int w = e / 104, i = e - w * 104;
    float v = 0.f;
    if (i < 100 && w >= wmin) v = hid[(size_t)(q - 39 + w) * HH + i];
    mem_l[e] = v;
  }
  // stage the gm window into LDS (f16): removes global loads from the scan chain
  for (int e = tid; e < 40 * 300; e += 320){
    int w = e / 300, j = e - w * 300;
    float v = (w >= wmin) ? gm[(size_t)(q - 39 + w) * 300 + j] : 0.f;
    g_l[e] = (_Float16)v;
  }
  if (tid < 300){
    #pragma unroll
    for (int i = 0; i < 25; ++i)
      *(float4*)&wreg[4 * i] = *(const float4*)&Whh[(size_t)tid * 100 + 4 * i];
  }
  __syncthreads();

  for (int hop = 0; hop < 3; ++hop){
    // --- attention: scores ---
    if (tid < 40){
      float a0 = 0, a1 = 0, a2 = 0, a3 = 0;
      const float* mr = &mem_l[tid * 104];
      #pragma unroll
      for (int i = 0; i < 25; ++i){
        float4 m4 = *(const float4*)&mr[4 * i];
        float4 q4 = *(const float4*)&q_l[4 * i];
        a0 += m4.x * q4.x; a1 += m4.y * q4.y; a2 += m4.z * q4.z; a3 += m4.w * q4.w;
      }
      sc_l[tid] = (tid >= wmin) ? ((a0 + a1) + (a2 + a3)) : -1e10f;
    }
    __syncthreads();
    if (tid < 64){
      float v = (tid < 40) ? sc_l[tid] : -3e38f;
      float m = v;
      #pragma unroll
      for (int off = 32; off; off >>= 1) m = fmaxf(m, __shfl_xor(m, off));
      float e = (tid < 40) ? __expf(v - m) : 0.f;
      float ssum = e;
      #pragma unroll
      for (int off = 32; off; off >>= 1) ssum += __shfl_xor(ssum, off);
      if (tid < 40) sc_l[tid] = e * frcp(ssum);
    }
    __syncthreads();
    // --- attention: context + query update ---
    if (tid < 50){
      float c0 = 0.f, c1 = 0.f;
      for (int w = wmin; w < 40; ++w){
        float a = sc_l[w];
        float2 mv = *(const float2*)&mem_l[w * 104 + 2 * tid];
        c0 += a * mv.x; c1 += a * mv.y;
      }
      float q0 = ftanh(q_l[2 * tid]     + c0);
      float q1 = ftanh(q_l[2 * tid + 1] + c1);
      *(float2*)&q_l[2 * tid] = make_float2(q0, q1);
      if (hop == 2)
        *(float2*)&scont[(size_t)(q + 1) * HH + 2 * tid] = make_float2(q0, q1);
    }
    if (hop == 2) break;

    if (hop == 1){
      // g_l = mem @ Wih^T + bih  (mem is post-scan1 state; overwrites gm staging)
      if (tid < 300){
        #pragma unroll
        for (int i = 0; i < 25; ++i)
          *(float4*)&wreg[4 * i] = *(const float4*)&Wih[(size_t)tid * 100 + 4 * i];
        for (int w = 0; w < 40; ++w){
          float a0 = 0, a1 = 0, a2 = 0, a3 = 0;
          const float* mr = &mem_l[w * 104];
          #pragma unroll
          for (int i = 0; i < 25; ++i){
            float4 m4 = *(const float4*)&mr[4 * i];
            a0 += m4.x * wreg[4*i]; a1 += m4.y * wreg[4*i+1];
            a2 += m4.z * wreg[4*i+2]; a3 += m4.w * wreg[4*i+3];
          }
          g_l[w * 300 + tid] = (_Float16)((a0 + a1) + (a2 + a3) + bi_l[tid]);
        }
        // restore Whh for scan2
        #pragma unroll
        for (int i = 0; i < 25; ++i)
          *(float4*)&wreg[4 * i] = *(const float4*)&Whh[(size_t)tid * 100 + 4 * i];
      }
    }

    // --- memory GRU scan over the 40 slots ---
    if (tid < HH) hbuf[tid] = 0.f;
    __syncthreads();   // also orders g_l writes (hop1) before scan reads
    for (int w = 0; w < 40; ++w){
      if (tid < 300){
        float a0 = 0, a1 = 0, a2 = 0, a3 = 0;
        #pragma unroll
        for (int i = 0; i < 25; ++i){
          float4 h4 = *(const float4*)&hbuf[4 * i];
          a0 += h4.x * wreg[4*i]; a1 += h4.y * wreg[4*i+1];
          a2 += h4.z * wreg[4*i+2]; a3 += h4.w * wreg[4*i+3];
        }
        gh_l[tid] = (a0 + a1) + (a2 + a3) + bh;
      }
      __syncthreads();
      if (tid < HH){
        float o = hbuf[tid];
        if (w >= wmin){
          const _Float16* gp = &g_l[w * 300];
          float gir = (float)gp[tid], giz = (float)gp[tid + 100], gin = (float)gp[tid + 200];
          float r = sigm(gir + gh_l[tid]);
          float z = sigm(giz + gh_l[tid + 100]);
          float n = ftanh(gin + r * gh_l[tid + 200]);
          o = (1.f - z) * n + z * o;
        }
        hbuf[tid] = o;
        mem_l[w * 104 + tid] = o;   // scan emits hm at every slot
      }
      __syncthreads();
    }
  }
}

// ---------------- Kernel 6: classifier + log_softmax ----------------
__global__ __launch_bounds__(256) void k_cls(const float* __restrict__ su, const float* __restrict__ scont,
    const float* __restrict__ Wcls, const float* __restrict__ bcls, float* __restrict__ out)
{
  __shared__ float wl[HH * NCC];
  __shared__ float bl[NCC];
  const int tid = threadIdx.x;
  for (int e = tid; e < HH * NCC; e += 256) wl[e] = Wcls[e];
  if (tid < NCC) bl[tid] = bcls[tid];
  __syncthreads();
  int r = blockIdx.x * 256 + tid;
  if (r < TT){
    const float* v = (r == 0) ? su : (scont + (size_t)r * HH);
    float l[NCC];
    #pragma unroll
    for (int c = 0; c < NCC; ++c) l[c] = bl[c];
    for (int h = 0; h < HH; ++h){
      float x = v[h];
      #pragma unroll
      for (int c = 0; c < NCC; ++c) l[c] += x * wl[h * NCC + c];
    }
    float m = l[0];
    #pragma unroll
    for (int c = 1; c < NCC; ++c) m = fmaxf(m, l[c]);
    float ssum = 0.f;
    #pragma unroll
    for (int c = 0; c < NCC; ++c) ssum += __expf(l[c] - m);
    float lse = m + __logf(ssum);
    #pragma unroll
    for (int c = 0; c < NCC; ++c) out[(size_t)r * NCC + c] = l[c] - lse;
  }
}

extern "C" void kernel_launch(void* const* d_in, const int* in_sizes, int n_in,
                              void* d_out, int out_size, void* d_ws, size_t ws_size,
                              hipStream_t stream)
{
  const int* sents  = (const int*)d_in[0];
  // d_in[1] = lengths (unused by the reference)
  const float* emb    = (const float*)d_in[2];
  const float* Wc3    = (const float*)d_in[3];  const float* bc3 = (const float*)d_in[4];
  const float* Wc4    = (const float*)d_in[5];  const float* bc4 = (const float*)d_in[6];
  const float* Wc5    = (const float*)d_in[7];  const float* bc5 = (const float*)d_in[8];
  const float* Wt     = (const float*)d_in[9];  const float* bt  = (const float*)d_in[10];
  const float* Wih_c  = (const float*)d_in[11]; const float* Whh_c = (const float*)d_in[12];
  const float* bih_c  = (const float*)d_in[13]; const float* bhh_c = (const float*)d_in[14];
  const float* Wih_m  = (const float*)d_in[15]; const float* Whh_m = (const float*)d_in[16];
  const float* bih_m  = (const float*)d_in[17]; const float* bhh_m = (const float*)d_in[18];
  const float* Wcls   = (const float*)d_in[19]; const float* bcls  = (const float*)d_in[20];

  float* ws    = (float*)d_ws;
  float* su    = ws;                  // 2048*100
  float* gic   = su  + 204800;        // 2047*300
  float* hid   = gic + 614100;        // 2047*100
  float* gm    = hid + 204700;        // 2047*300
  float* scont = gm  + 614100;        // 2048*100 (row 0 unused)

  k_cnn <<<TT,      256, 0, stream>>>(sents, emb, Wc3, bc3, Wc4, bc4, Wc5, bc5, Wt, bt, su);
  k_gi  <<<TT - 1,  320, 0, stream>>>(su, Wih_c, bih_c, gic);
  k_scan<<<1,       320, 0, stream>>>(gic, Whh_c, bhh_c, hid, TT - 1);
  k_gi  <<<TT - 1,  320, 0, stream>>>(hid, Wih_m, bih_m, gm);
  k_att <<<TT - 1,  320, 0, stream>>>(su, hid, gm, Wih_m, Whh_m, bih_m, bhh_m, scont);
  k_cls <<<(TT + 255) / 256, 256, 0, stream>>>(su, scont, Wcls, bcls, (float*)d_out);
}

// Round 5
// 3531.841 us; speedup vs baseline: 1.7668x; 1.2427x over previous
//
#include <hip/hip_runtime.h>

#define TT 2048
#define LL 50
#define DD 300
#define HH 100
#define NCC 7

typedef unsigned short u16;
typedef unsigned int u32;
typedef _Float16 f16x2 __attribute__((ext_vector_type(2)));

__device__ __forceinline__ u32 fkey(float f){ u32 u; __builtin_memcpy(&u, &f, 4); return (u & 0x80000000u) ? ~u : (u | 0x80000000u); }
__device__ __forceinline__ float funkey(u32 k){ u32 u = (k & 0x80000000u) ? (k & 0x7FFFFFFFu) : ~k; float f; __builtin_memcpy(&f, &u, 4); return f; }
__device__ __forceinline__ float frcp(float x){ return __builtin_amdgcn_rcpf(x); }
__device__ __forceinline__ float sigm(float x){ return frcp(1.f + __expf(-x)); }
__device__ __forceinline__ float ftanh(float x){ return 1.f - 2.f * frcp(1.f + __expf(2.f * x)); }

#if defined(__has_builtin)
#if __has_builtin(__builtin_amdgcn_fdot2)
#define HAS_FDOT2 1
#endif
#endif
__device__ __forceinline__ float fdot2(f16x2 a, f16x2 b, float c){
#ifdef HAS_FDOT2
  return __builtin_amdgcn_fdot2(a, b, c, false);
#else
  return c + (float)a.x * (float)b.x + (float)a.y * (float)b.y;
#endif
}
__device__ __forceinline__ f16x2 pk(float x, float y){ f16x2 r; r.x = (_Float16)x; r.y = (_Float16)y; return r; }

// ---------------- Kernel 1: embedding + TextCNN(3,4,5) + max-relu + s_utt ----------------
#define WROW 304
__device__ __forceinline__ int widx(int pos, int d){ return pos * WROW + (pos >> 3) * 4 + d; }
#define WSZ (52 * WROW + 7 * 4)

__global__ __launch_bounds__(256) void k_cnn(const int* __restrict__ sents,
    const float* __restrict__ emb,
    const float* __restrict__ Wc3, const float* __restrict__ bc3,
    const float* __restrict__ Wc4, const float* __restrict__ bc4,
    const float* __restrict__ Wc5, const float* __restrict__ bc5,
    const float* __restrict__ Wt,  const float* __restrict__ bt,
    float* __restrict__ su)
{
  __shared__ float w[WSZ];
  __shared__ int ids[LL];
  __shared__ u32 feats_u[192];
  const int tid = threadIdx.x;
  const int s = blockIdx.x;

  if (tid < LL) ids[tid] = sents[s * LL + tid];
  for (int e = tid; e < WSZ; e += 256) w[e] = 0.f;
  if (tid < 192) feats_u[tid] = 0u;
  __syncthreads();
  for (int e = tid; e < LL * 75; e += 256){
    int l = e / 75, d4 = (e - l * 75) * 4;
    *(float4*)&w[widx(l, d4)] = *(const float4*)&emb[(size_t)ids[l] * DD + d4];
  }
  __syncthreads();

  for (int task = tid; task < 288; task += 256){
    int F  = task / 6;
    int pc = task - F * 6;
    int kk, fbase, colbase; const float* W;
    if (F < 16){ kk = 3; fbase = F * 4;         W = Wc3; colbase = fbase; }
    else if (F < 32){ kk = 4; fbase = (F-16)*4; W = Wc4; colbase = 64 + fbase; }
    else { kk = 5; fbase = (F-32)*4;            W = Wc5; colbase = 128 + fbase; }
    int pos0 = pc * 8;
    float acc[4][8];
    #pragma unroll
    for (int fi = 0; fi < 4; ++fi)
      #pragma unroll
      for (int p = 0; p < 8; ++p) acc[fi][p] = 0.f;

    for (int j = 0; j < kk; ++j){
      const float* wr = W + (size_t)(fbase * kk + j) * DD;
      int rb[8];
      #pragma unroll
      for (int p = 0; p < 8; ++p) rb[p] = widx(pos0 + p + j, 0);
      for (int d = 0; d < DD; d += 4){
        float4 a[8];
        #pragma unroll
        for (int p = 0; p < 8; ++p) a[p] = *(const float4*)&w[rb[p] + d];
        #pragma unroll
        for (int fi = 0; fi < 4; ++fi){
          float4 wv = *(const float4*)(wr + (size_t)fi * kk * DD + d);
          #pragma unroll
          for (int p = 0; p < 8; ++p)
            acc[fi][p] += a[p].x * wv.x + a[p].y * wv.y + a[p].z * wv.z + a[p].w * wv.w;
        }
      }
    }
    int Pk = LL - kk + 1;
    #pragma unroll
    for (int fi = 0; fi < 4; ++fi){
      float m = -1e30f;
      #pragma unroll
      for (int p = 0; p < 8; ++p) if (pos0 + p < Pk) m = fmaxf(m, acc[fi][p]);
      atomicMax(&feats_u[colbase + fi], fkey(m));
    }
  }
  __syncthreads();
  if (tid < 192){
    float m = funkey(feats_u[tid]);
    float bias = (tid < 64) ? bc3[tid] : ((tid < 128) ? bc4[tid - 64] : bc5[tid - 128]);
    feats_u[tid] = __float_as_uint(fmaxf(0.f, m + bias));
  }
  __syncthreads();
  if (tid < HH){
    float acc = bt[tid];
    for (int c = 0; c < 192; ++c)
      acc += __uint_as_float(feats_u[c]) * Wt[c * HH + tid];
    su[(size_t)s * HH + tid] = ftanh(acc);
  }
}

// ---------------- Kernel 2/4: gi = src @ Wih^T + bih   (rows x 300) ----------------
__global__ __launch_bounds__(320) void k_gi(const float* __restrict__ src,
    const float* __restrict__ W, const float* __restrict__ b, float* __restrict__ dst)
{
  __shared__ float x[HH];
  const int t = blockIdx.x, tid = threadIdx.x;
  if (tid < HH) x[tid] = src[(size_t)t * HH + tid];
  __syncthreads();
  if (tid < 300){
    float acc = b[tid];
    const float* wr = W + (size_t)tid * HH;
    #pragma unroll
    for (int i = 0; i < 25; ++i){
      float4 wv = *(const float4*)(wr + 4 * i);
      float4 xv = *(const float4*)&x[4 * i];
      acc += xv.x * wv.x + xv.y * wv.y + xv.z * wv.z + xv.w * wv.w;
    }
    dst[(size_t)t * 300 + tid] = acc;
  }
}

// ---------------- Kernel 3: sequential context-GRU scan (1 workgroup, 128 thr) ----------------
// Lane j<100 owns hidden unit j: holds Whh rows j, j+100, j+200 packed f16x2 in
// registers; computes all 3 gate dots in-lane (no gh through LDS) -> ONE barrier
// per step. h state: f32 in-register (exact), f16 double-buffered in LDS for the
// broadcast matvec input (13 b128/wave/step vs 25 f32).
#define CH 16
__global__ __launch_bounds__(128) void k_scan(const float* __restrict__ gi,
    const float* __restrict__ Whh, const float* __restrict__ bhh,
    float* __restrict__ hid, int steps)
{
  __shared__ __attribute__((aligned(16))) _Float16 hA[104];
  __shared__ __attribute__((aligned(16))) _Float16 hB[104];
  __shared__ float gi_buf[CH * 300];
  __shared__ float hid_buf[CH * HH];
  const int tid = threadIdx.x;
  f16x2 wr[52], wz[52], wn[52];
  float br = 0.f, bz = 0.f, bn = 0.f, hreg = 0.f;
  if (tid < HH){
    const float* r0 = Whh + (size_t)tid * 100;
    const float* r1 = Whh + (size_t)(tid + 100) * 100;
    const float* r2 = Whh + (size_t)(tid + 200) * 100;
    #pragma unroll
    for (int i = 0; i < 25; ++i){
      float4 a = *(const float4*)(r0 + 4 * i);
      wr[2*i] = pk(a.x, a.y); wr[2*i+1] = pk(a.z, a.w);
      float4 b = *(const float4*)(r1 + 4 * i);
      wz[2*i] = pk(b.x, b.y); wz[2*i+1] = pk(b.z, b.w);
      float4 c = *(const float4*)(r2 + 4 * i);
      wn[2*i] = pk(c.x, c.y); wn[2*i+1] = pk(c.z, c.w);
    }
    br = bhh[tid]; bz = bhh[tid + 100]; bn = bhh[tid + 200];
  }
  #pragma unroll
  for (int i = 50; i < 52; ++i){ wr[i] = pk(0,0); wz[i] = pk(0,0); wn[i] = pk(0,0); }
  if (tid < 104){ hA[tid] = (_Float16)0.f; hB[tid] = (_Float16)0.f; }
  {
    int c0 = (steps < CH ? steps : CH) * 75;
    for (int e = tid; e < c0; e += 128)
      ((float4*)gi_buf)[e] = ((const float4*)gi)[e];
  }
  __syncthreads();

  int t0 = 0;
  while (t0 < steps){
    int cnt = steps - t0; if (cnt > CH) cnt = CH;
    for (int s = 0; s < cnt; ++s){
      const _Float16* hs = ((t0 + s) & 1) ? hB : hA;   // read state t
      _Float16*       hd = ((t0 + s) & 1) ? hA : hB;   // write state t+1
      float ar0=0, ar1=0, az0=0, az1=0, an0=0, an1=0;
      const float4* hq = (const float4*)hs;
      #pragma unroll
      for (int g = 0; g < 13; ++g){
        float4 hv = hq[g];
        f16x2 p0 = __builtin_bit_cast(f16x2, hv.x), p1 = __builtin_bit_cast(f16x2, hv.y);
        f16x2 p2 = __builtin_bit_cast(f16x2, hv.z), p3 = __builtin_bit_cast(f16x2, hv.w);
        ar0 = fdot2(wr[4*g  ], p0, ar0); ar1 = fdot2(wr[4*g+1], p1, ar1);
        az0 = fdot2(wz[4*g  ], p0, az0); az1 = fdot2(wz[4*g+1], p1, az1);
        an0 = fdot2(wn[4*g  ], p0, an0); an1 = fdot2(wn[4*g+1], p1, an1);
        ar0 = fdot2(wr[4*g+2], p2, ar0); ar1 = fdot2(wr[4*g+3], p3, ar1);
        az0 = fdot2(wz[4*g+2], p2, az0); az1 = fdot2(wz[4*g+3], p3, az1);
        an0 = fdot2(wn[4*g+2], p2, an0); an1 = fdot2(wn[4*g+3], p3, an1);
      }
      if (tid < HH){
        const float* gp = gi_buf + s * 300;
        float r = sigm(gp[tid]       + br + ar0 + ar1);
        float z = sigm(gp[tid + 100] + bz + az0 + az1);
        float n = ftanh(gp[tid + 200] + r * (bn + an0 + an1));
        float o = (1.f - z) * n + z * hreg;
        hreg = o;
        hd[tid] = (_Float16)o;
        hid_buf[s * HH + tid] = o;
      }
      __syncthreads();
    }
    // chunk boundary: flush hid, stage next gi chunk
    for (int e = tid; e < cnt * 25; e += 128)
      ((float4*)(hid + (size_t)t0 * HH))[e] = ((const float4*)hid_buf)[e];
    int nt0 = t0 + cnt;
    int ncnt = steps - nt0; if (ncnt > CH) ncnt = CH; if (ncnt < 0) ncnt = 0;
    for (int e = tid; e < ncnt * 75; e += 128)
      ((float4*)gi_buf)[e] = ((const float4*)(gi + (size_t)nt0 * 300))[e];
    __syncthreads();
    t0 = nt0;
  }
}

// ---------------- Kernel 5: 3-hop windowed memory attention (1 block / query) ----------------
// f16 matvec inputs: hb16 (scan state), mem16 (gi2 input); weights packed f16x2
// in 52 VGPRs. f32 kept for state/scores/output.
__global__ __launch_bounds__(320) void k_att(
    const float* __restrict__ su, const float* __restrict__ hid, const float* __restrict__ gm,
    const float* __restrict__ Wih, const float* __restrict__ Whh,
    const float* __restrict__ bih, const float* __restrict__ bhh,
    float* __restrict__ scont)
{
  __shared__ float mem_l[40 * 104];
  __shared__ __attribute__((aligned(16))) _Float16 mem16[40 * 104];
  __shared__ float hbuf[HH];
  __shared__ __attribute__((aligned(16))) _Float16 hb16[104];
  __shared__ float gh_l[300];
  __shared__ float q_l[104];
  __shared__ float sc_l[40];
  __shared__ float bi_l[300];
  __shared__ _Float16 g_l[40 * 300];   // hop0: staged gm; hop1: computed gi2
  const int tid = threadIdx.x;
  const int q = blockIdx.x;                 // query q -> sentence q+1
  int wmin = 39 - q; if (wmin < 0) wmin = 0;
  f16x2 wreg[52];
  float bh = 0.f;

  if (tid < 300){ bi_l[tid] = bih[tid]; bh = bhh[tid]; }
  if (tid < 104) q_l[tid] = (tid < 100) ? su[(size_t)(q + 1) * HH + tid] : 0.f;
  for (int e = tid; e < 40 * 104; e += 320){
    int w = e / 104, i = e - w * 104;
    float v = 0.f;
    if (i < 100 && w >= wmin) v = hid[(size_t)(q - 39 + w) * HH + i];
    mem_l[e] = v;
    mem16[e] = (_Float16)v;   // also zeroes pads (cols 100..103)
  }
  for (int e = tid; e < 40 * 300; e += 320){
    int w = e / 300, j = e - w * 300;
    float v = (w >= wmin) ? gm[(size_t)(q - 39 + w) * 300 + j] : 0.f;
    g_l[e] = (_Float16)v;
  }
  if (tid < 300){
    const float* r0 = Whh + (size_t)tid * 100;
    #pragma unroll
    for (int i = 0; i < 25; ++i){
      float4 a = *(const float4*)(r0 + 4 * i);
      wreg[2*i] = pk(a.x, a.y); wreg[2*i+1] = pk(a.z, a.w);
    }
  }
  wreg[50] = pk(0,0); wreg[51] = pk(0,0);
  __syncthreads();

  for (int hop = 0; hop < 3; ++hop){
    // --- attention: scores ---
    if (tid < 40){
      float a0 = 0, a1 = 0, a2 = 0, a3 = 0;
      const float* mr = &mem_l[tid * 104];
      #pragma unroll
      for (int i = 0; i < 25; ++i){
        float4 m4 = *(const float4*)&mr[4 * i];
        float4 q4 = *(const float4*)&q_l[4 * i];
        a0 += m4.x * q4.x; a1 += m4.y * q4.y; a2 += m4.z * q4.z; a3 += m4.w * q4.w;
      }
      sc_l[tid] = (tid >= wmin) ? ((a0 + a1) + (a2 + a3)) : -1e10f;
    }
    __syncthreads();
    if (tid < 64){
      float v = (tid < 40) ? sc_l[tid] : -3e38f;
      float m = v;
      #pragma unroll
      for (int off = 32; off; off >>= 1) m = fmaxf(m, __shfl_xor(m, off));
      float e = (tid < 40) ? __expf(v - m) : 0.f;
      float ssum = e;
      #pragma unroll
      for (int off = 32; off; off >>= 1) ssum += __shfl_xor(ssum, off);
      if (tid < 40) sc_l[tid] = e * frcp(ssum);
    }
    __syncthreads();
    // --- attention: context + query update ---
    if (tid < 50){
      float c0 = 0.f, c1 = 0.f;
      for (int w = wmin; w < 40; ++w){
        float a = sc_l[w];
        float2 mv = *(const float2*)&mem_l[w * 104 + 2 * tid];
        c0 += a * mv.x; c1 += a * mv.y;
      }
      float q0 = ftanh(q_l[2 * tid]     + c0);
      float q1 = ftanh(q_l[2 * tid + 1] + c1);
      *(float2*)&q_l[2 * tid] = make_float2(q0, q1);
      if (hop == 2)
        *(float2*)&scont[(size_t)(q + 1) * HH + 2 * tid] = make_float2(q0, q1);
    }
    if (hop == 2) break;

    if (hop == 1){
      // g_l = mem @ Wih^T + bih  (mem16 is post-scan1 state)
      if (tid < 300){
        const float* r0 = Wih + (size_t)tid * 100;
        #pragma unroll
        for (int i = 0; i < 25; ++i){
          float4 a = *(const float4*)(r0 + 4 * i);
          wreg[2*i] = pk(a.x, a.y); wreg[2*i+1] = pk(a.z, a.w);
        }
        for (int w = 0; w < 40; ++w){
          float a0 = 0, a1 = 0;
          const float4* mq = (const float4*)&mem16[w * 104];
          #pragma unroll
          for (int g = 0; g < 13; ++g){
            float4 hv = mq[g];
            a0 = fdot2(wreg[4*g  ], __builtin_bit_cast(f16x2, hv.x), a0);
            a1 = fdot2(wreg[4*g+1], __builtin_bit_cast(f16x2, hv.y), a1);
            a0 = fdot2(wreg[4*g+2], __builtin_bit_cast(f16x2, hv.z), a0);
            a1 = fdot2(wreg[4*g+3], __builtin_bit_cast(f16x2, hv.w), a1);
          }
          g_l[w * 300 + tid] = (_Float16)(a0 + a1 + bi_l[tid]);
        }
        // restore Whh for scan2
        const float* rh = Whh + (size_t)tid * 100;
        #pragma unroll
        for (int i = 0; i < 25; ++i){
          float4 a = *(const float4*)(rh + 4 * i);
          wreg[2*i] = pk(a.x, a.y); wreg[2*i+1] = pk(a.z, a.w);
        }
      }
    }

    // --- memory GRU scan over the 40 slots ---
    if (tid < HH) hbuf[tid] = 0.f;
    if (tid < 104) hb16[tid] = (_Float16)0.f;
    __syncthreads();   // also orders g_l writes (hop1) before scan reads
    for (int w = 0; w < 40; ++w){
      if (tid < 300){
        float a0 = 0, a1 = 0;
        const float4* hq = (const float4*)hb16;
        #pragma unroll
        for (int g = 0; g < 13; ++g){
          float4 hv = hq[g];
          a0 = fdot2(wreg[4*g  ], __builtin_bit_cast(f16x2, hv.x), a0);
          a1 = fdot2(wreg[4*g+1], __builtin_bit_cast(f16x2, hv.y), a1);
          a0 = fdot2(wreg[4*g+2], __builtin_bit_cast(f16x2, hv.z), a0);
          a1 = fdot2(wreg[4*g+3], __builtin_bit_cast(f16x2, hv.w), a1);
        }
        gh_l[tid] = a0 + a1 + bh;
      }
      __syncthreads();
      if (tid < HH){
        float o = hbuf[tid];
        if (w >= wmin){
          const _Float16* gp = &g_l[w * 300];
          float gir = (float)gp[tid], giz = (float)gp[tid + 100], gin = (float)gp[tid + 200];
          float r = sigm(gir + gh_l[tid]);
          float z = sigm(giz + gh_l[tid + 100]);
          float n = ftanh(gin + r * gh_l[tid + 200]);
          o = (1.f - z) * n + z * o;
        }
        hbuf[tid] = o;
        hb16[tid] = (_Float16)o;
        mem_l[w * 104 + tid] = o;
        mem16[w * 104 + tid] = (_Float16)o;
      }
      __syncthreads();
    }
  }
}

// ---------------- Kernel 6: classifier + log_softmax ----------------
__global__ __launch_bounds__(256) void k_cls(const float* __restrict__ su, const float* __restrict__ scont,
    const float* __restrict__ Wcls, const float* __restrict__ bcls, float* __restrict__ out)
{
  __shared__ float wl[HH * NCC];
  __shared__ float bl[NCC];
  const int tid = threadIdx.x;
  for (int e = tid; e < HH * NCC; e += 256) wl[e] = Wcls[e];
  if (tid < NCC) bl[tid] = bcls[tid];
  __syncthreads();
  int r = blockIdx.x * 256 + tid;
  if (r < TT){
    const float* v = (r == 0) ? su : (scont + (size_t)r * HH);
    float l[NCC];
    #pragma unroll
    for (int c = 0; c < NCC; ++c) l[c] = bl[c];
    for (int h = 0; h < HH; ++h){
      float x = v[h];
      #pragma unroll
      for (int c = 0; c < NCC; ++c) l[c] += x * wl[h * NCC + c];
    }
    float m = l[0];
    #pragma unroll
    for (int c = 1; c < NCC; ++c) m = fmaxf(m, l[c]);
    float ssum = 0.f;
    #pragma unroll
    for (int c = 0; c < NCC; ++c) ssum += __expf(l[c] - m);
    float lse = m + __logf(ssum);
    #pragma unroll
    for (int c = 0; c < NCC; ++c) out[(size_t)r * NCC + c] = l[c] - lse;
  }
}

extern "C" void kernel_launch(void* const* d_in, const int* in_sizes, int n_in,
                              void* d_out, int out_size, void* d_ws, size_t ws_size,
                              hipStream_t stream)
{
  const int* sents  = (const int*)d_in[0];
  // d_in[1] = lengths (unused by the reference)
  const float* emb    = (const float*)d_in[2];
  const float* Wc3    = (const float*)d_in[3];  const float* bc3 = (const float*)d_in[4];
  const float* Wc4    = (const float*)d_in[5];  const float* bc4 = (const float*)d_in[6];
  const float* Wc5    = (const float*)d_in[7];  const float* bc5 = (const float*)d_in[8];
  const float* Wt     = (const float*)d_in[9];  const float* bt  = (const float*)d_in[10];
  const float* Wih_c  = (const float*)d_in[11]; const float* Whh_c = (const float*)d_in[12];
  const float* bih_c  = (const float*)d_in[13]; const float* bhh_c = (const float*)d_in[14];
  const float* Wih_m  = (const float*)d_in[15]; const float* Whh_m = (const float*)d_in[16];
  const float* bih_m  = (const float*)d_in[17]; const float* bhh_m = (const float*)d_in[18];
  const float* Wcls   = (const float*)d_in[19]; const float* bcls  = (const float*)d_in[20];

  float* ws    = (float*)d_ws;
  float* su    = ws;                  // 2048*100
  float* gic   = su  + 204800;        // 2047*300
  float* hid   = gic + 614100;        // 2047*100
  float* gm    = hid + 204700;        // 2047*300
  float* scont = gm  + 614100;        // 2048*100 (row 0 unused)

  k_cnn <<<TT,      256, 0, stream>>>(sents, emb, Wc3, bc3, Wc4, bc4, Wc5, bc5, Wt, bt, su);
  k_gi  <<<TT - 1,  320, 0, stream>>>(su, Wih_c, bih_c, gic);
  k_scan<<<1,       128, 0, stream>>>(gic, Whh_c, bhh_c, hid, TT - 1);
  k_gi  <<<TT - 1,  320, 0, stream>>>(hid, Wih_m, bih_m, gm);
  k_att <<<TT - 1,  320, 0, stream>>>(su, hid, gm, Wih_m, Whh_m, bih_m, bhh_m, scont);
  k_cls <<<(TT + 255) / 256, 256, 0, stream>>>(su, scont, Wcls, bcls, (float*)d_out);
}